// Round 6
// baseline (137.252 us; speedup 1.0000x reference)
//
#include <hip/hip_runtime.h>
#include <stdint.h>

#define B_ROWS 16384
#define C_CLS  2000
#define C_PAD  2048
#define F_DIM  1024
#define KT     16                      // K-tiles of 64
#define NRB    64                      // gemm row blocks (256 rows)
#define NCB    8                       // gemm col blocks (256 cols)
#define REG_B  16384                   // bytes per (tile,khalf) region: 256 rows x 32 k bf16
#define PANEL_B ((size_t)KT * 2 * REG_B)  // 512 KB per 256-row/col panel

typedef float  f32x4  __attribute__((ext_vector_type(4)));
typedef __bf16 bf16x8 __attribute__((ext_vector_type(8)));
typedef unsigned short u16x8 __attribute__((ext_vector_type(8)));

__device__ __forceinline__ unsigned short f2bf(float f) {
    union { float f; uint32_t u; } v; v.f = f;
    uint32_t u = v.u;
    return (unsigned short)((u + 0x7fffu + ((u >> 16) & 1u)) >> 16);  // RNE
}

__device__ __forceinline__ void gl_lds16(const void* g, void* l) {
    __builtin_amdgcn_global_load_lds(
        (const __attribute__((address_space(1))) unsigned int*)g,
        (__attribute__((address_space(3))) unsigned int*)l, 16, 0, 0);
}

// file layout A: [rb][kt][khalf][rhalf(128rows)][r(128)][k(32)] bf16, row-major 64B rows
// file layout B: [cb][kt][khalf][chalf(128cols)][c(128)][k(32)]

// ---- prepass A: feat -> bf16 regions, fused fisher. grid 512 = rt128(128) x g(4) ----
__global__ __launch_bounds__(256)
void prepA_kernel(const float* __restrict__ feat, const int* __restrict__ labels,
                  const float* __restrict__ centers,
                  char* __restrict__ A_pre, float* __restrict__ fisher_part)
{
    const int rt = blockIdx.x >> 2, g = blockIdx.x & 3;
    const int rb = rt >> 1, rhalf = rt & 1;
    const int tid = threadIdx.x;
    const int r = tid >> 1, h = tid & 1;
    const int grow = rt * 128 + r;
    const int lab = labels[grow];
    const float* frow = feat    + (size_t)grow * F_DIM;
    const float* crow = centers + (size_t)lab  * F_DIM;
    char* dbase = A_pre + (size_t)rb * PANEL_B + rhalf * 8192 + r * 64;
    float facc = 0.f;
    #pragma unroll
    for (int t = 0; t < 2; ++t) {
        const int kt = g * 4 + h * 2 + t;
        #pragma unroll
        for (int kh = 0; kh < 2; ++kh) {
            const int kb = kt * 64 + kh * 32;
            char* dst = dbase + (kt * 2 + kh) * REG_B;
            #pragma unroll
            for (int cc = 0; cc < 4; ++cc) {          // 4 chunks of 8 feats
                float4 f0 = *(const float4*)(frow + kb + cc * 8);
                float4 f1 = *(const float4*)(frow + kb + cc * 8 + 4);
                float4 c0 = *(const float4*)(crow + kb + cc * 8);
                float4 c1 = *(const float4*)(crow + kb + cc * 8 + 4);
                float d0 = f0.x - c0.x, d1 = f0.y - c0.y, d2 = f0.z - c0.z, d3 = f0.w - c0.w;
                float d4 = f1.x - c1.x, d5 = f1.y - c1.y, d6 = f1.z - c1.z, d7 = f1.w - c1.w;
                facc += d0*d0 + d1*d1 + d2*d2 + d3*d3 + d4*d4 + d5*d5 + d6*d6 + d7*d7;
                u16x8 o = { f2bf(f0.x), f2bf(f0.y), f2bf(f0.z), f2bf(f0.w),
                            f2bf(f1.x), f2bf(f1.y), f2bf(f1.z), f2bf(f1.w) };
                *(u16x8*)(dst + cc * 16) = o;
            }
        }
    }
    for (int d = 32; d >= 1; d >>= 1) facc += __shfl_xor(facc, d);
    __shared__ float redw[4];
    const int wid = tid >> 6, lane = tid & 63;
    if (lane == 0) redw[wid] = facc;
    __syncthreads();
    if (tid == 0) fisher_part[blockIdx.x] = redw[0] + redw[1] + redw[2] + redw[3];
}

// ---- prepass B: W -> bf16 regions, zero-pad; bias pad folded. grid 128 = ct(16) x ktg(8) ----
__global__ __launch_bounds__(256)
void prepB_kernel(const float* __restrict__ W, const float* __restrict__ bias,
                  char* __restrict__ B_pre, float* __restrict__ bias_pad)
{
    const int ct = blockIdx.x >> 3, ktg = blockIdx.x & 7;
    const int cb = ct >> 1, chalf = ct & 1;
    const int tid = threadIdx.x;
    const int rcol = tid >> 1, h = tid & 1;
    const int gc = ct * 128 + rcol;
    const int kt = ktg * 2 + h;
    char* dbase = B_pre + (size_t)cb * PANEL_B + chalf * 8192 + rcol * 64;
    #pragma unroll
    for (int kh = 0; kh < 2; ++kh) {
        char* dst = dbase + (kt * 2 + kh) * REG_B;
        if (gc < C_CLS) {
            const float* src = W + (size_t)gc * F_DIM + kt * 64 + kh * 32;
            #pragma unroll
            for (int cc = 0; cc < 4; ++cc) {
                float4 f0 = *(const float4*)(src + cc * 8);
                float4 f1 = *(const float4*)(src + cc * 8 + 4);
                u16x8 o = { f2bf(f0.x), f2bf(f0.y), f2bf(f0.z), f2bf(f0.w),
                            f2bf(f1.x), f2bf(f1.y), f2bf(f1.z), f2bf(f1.w) };
                *(u16x8*)(dst + cc * 16) = o;
            }
        } else {
            u16x8 z = {0,0,0,0,0,0,0,0};
            #pragma unroll
            for (int cc = 0; cc < 4; ++cc) *(u16x8*)(dst + cc * 16) = z;
        }
    }
    if (blockIdx.x < C_PAD / 256) {
        const int i = blockIdx.x * 256 + tid;
        bias_pad[i] = (i < C_CLS) ? bias[i] : -1e30f;
    }
}

// ---- 256x256 MFMA GEMM, m201-style 8-phase pipeline, sum-exp epilogue ----
// LDS per buf (64KB): [A k0 16K][A k1 16K][B k0 16K][B k1 16K]; 2 bufs = 128KB
__global__ __launch_bounds__(512, 2)
void gemm_kernel(const int* __restrict__ labels, const float* __restrict__ biasp,
                 const char* __restrict__ A_pre, const char* __restrict__ B_pre,
                 float* __restrict__ s_part, float* __restrict__ tl_part)
{
    __shared__ alignas(128) char smem[131072];
    __shared__ float red2[256][4][2];

    const int cpx = gridDim.x >> 3;                 // XCD swizzle: same-XCD blocks share rb
    const int wg = (blockIdx.x & 7) * cpx + (blockIdx.x >> 3);
    const int cb = wg & 7;
    const int rb = wg >> 3;

    const int tid = threadIdx.x;
    const int w = tid >> 6, lane = tid & 63;
    const int l15 = lane & 15, lhi = lane >> 4;
    const int wr = w >> 2, wc = w & 3;

    const char* Asrc = A_pre + (size_t)rb * PANEL_B;
    const char* Bsrc = B_pre + (size_t)cb * PANEL_B;

    // ds_read byte offsets within a (A|B, khalf) region — plain row-major, conflict-free
    int aoff[8], boff[4];
    #pragma unroll
    for (int mi = 0; mi < 8; ++mi)
        aoff[mi] = wr * 8192 + (mi * 16 + l15) * 64 + lhi * 16;
    #pragma unroll
    for (int ni = 0; ni < 4; ++ni)
        boff[ni] = (wc >> 1) * 8192 + ((wc & 1) * 64 + ni * 16 + l15) * 64 + lhi * 16;

    f32x4 acc[8][4];
    #pragma unroll
    for (int mi = 0; mi < 8; ++mi)
        #pragma unroll
        for (int ni = 0; ni < 4; ++ni) acc[mi][ni] = (f32x4){0.f, 0.f, 0.f, 0.f};

    auto STAGE = [&](const char* srcreg, int ldsreg) {  // 16KB region, 2 loads/thread
        const char* s = srcreg + w * 2048 + lane * 16;
        char* d = smem + ldsreg + w * 2048;             // wave-uniform dst base
        gl_lds16(s, d);
        gl_lds16(s + 1024, d + 1024);
    };

    bf16x8 bv[4];

#define PHASE(BUFOFF, KF, MLO, LOADB, DOSTAGE, SREG, LREG) do {                       \
    const char* Ab_ = smem + (BUFOFF) + (KF) * 16384;                                 \
    const char* Bb_ = smem + (BUFOFF) + 32768 + (KF) * 16384;                         \
    bf16x8 af_[4];                                                                    \
    if (LOADB) {                                                                      \
        _Pragma("unroll")                                                             \
        for (int ni_ = 0; ni_ < 4; ++ni_)                                             \
            bv[ni_] = *(const bf16x8*)(Bb_ + boff[ni_]);                              \
    }                                                                                 \
    _Pragma("unroll")                                                                 \
    for (int mi_ = 0; mi_ < 4; ++mi_)                                                 \
        af_[mi_] = *(const bf16x8*)(Ab_ + aoff[(MLO) + mi_]);                         \
    __builtin_amdgcn_sched_barrier(0);                                                \
    if (DOSTAGE) STAGE(SREG, LREG);                                                   \
    asm volatile("s_waitcnt vmcnt(8)" ::: "memory");                                  \
    __builtin_amdgcn_sched_barrier(0);                                                \
    __builtin_amdgcn_s_barrier();                                                     \
    __builtin_amdgcn_sched_barrier(0);                                                \
    __builtin_amdgcn_s_setprio(1);                                                    \
    _Pragma("unroll")                                                                 \
    for (int mi_ = 0; mi_ < 4; ++mi_)                                                 \
        _Pragma("unroll")                                                             \
        for (int ni_ = 0; ni_ < 4; ++ni_)                                             \
            acc[(MLO) + mi_][ni_] = __builtin_amdgcn_mfma_f32_16x16x32_bf16(          \
                af_[mi_], bv[ni_], acc[(MLO) + mi_][ni_], 0, 0, 0);                   \
    __builtin_amdgcn_s_setprio(0);                                                    \
    __builtin_amdgcn_sched_barrier(0);                                                \
    __builtin_amdgcn_s_barrier();                                                     \
} while (0)

    // prologue: tile0 all regions + tile1 khalf0
    STAGE(Asrc,             0);       // A(0,k0)
    STAGE(Bsrc,             32768);   // B(0,k0)
    STAGE(Asrc + REG_B,     16384);   // A(0,k1)
    STAGE(Bsrc + REG_B,     49152);   // B(0,k1)
    STAGE(Asrc + 2 * REG_B, 65536);   // A(1,k0)
    STAGE(Bsrc + 2 * REG_B, 98304);   // B(1,k0)
    asm volatile("s_waitcnt vmcnt(4)" ::: "memory");
    __builtin_amdgcn_sched_barrier(0);
    __builtin_amdgcn_s_barrier();

    #pragma unroll 1
    for (int i = 0; i < 7; ++i) {
        const char* At = Asrc + (size_t)(4 * i) * REG_B;
        const char* Bt = Bsrc + (size_t)(4 * i) * REG_B;
        // buf0 = tile 2i, buf1 = tile 2i+1; stage map per region-lifetime analysis
        PHASE(0,     0, 0, 1, 1, At + 3 * REG_B,  81920);   // stage A(2i+1,k1) -> buf1.Ak1
        PHASE(0,     0, 4, 0, 1, Bt + 3 * REG_B, 114688);   // stage B(2i+1,k1) -> buf1.Bk1
        PHASE(0,     1, 0, 1, 1, At + 4 * REG_B,      0);   // stage A(2i+2,k0) -> buf0.Ak0
        PHASE(0,     1, 4, 0, 1, Bt + 4 * REG_B,  32768);   // stage B(2i+2,k0) -> buf0.Bk0
        PHASE(65536, 0, 0, 1, 1, At + 5 * REG_B,  16384);   // stage A(2i+2,k1) -> buf0.Ak1
        PHASE(65536, 0, 4, 0, 1, Bt + 5 * REG_B,  49152);   // stage B(2i+2,k1) -> buf0.Bk1
        PHASE(65536, 1, 0, 1, 1, At + 6 * REG_B,  65536);   // stage A(2i+3,k0) -> buf1.Ak0
        PHASE(65536, 1, 4, 0, 1, Bt + 6 * REG_B,  98304);   // stage B(2i+3,k0) -> buf1.Bk0
    }
    // tail i = 7: tiles 14 (buf0), 15 (buf1); only tile-15 k1 still needs staging
    PHASE(0,     0, 0, 1, 1, Asrc + 31 * REG_B,  81920);
    PHASE(0,     0, 4, 0, 1, Bsrc + 31 * REG_B, 114688);
    PHASE(0,     1, 0, 1, 0, Asrc, 0);
    PHASE(0,     1, 4, 0, 0, Asrc, 0);
    PHASE(65536, 0, 0, 1, 0, Asrc, 0);
    PHASE(65536, 0, 4, 0, 0, Asrc, 0);
    PHASE(65536, 1, 0, 1, 0, Asrc, 0);
    PHASE(65536, 1, 4, 0, 0, Asrc, 0);
#undef PHASE

    // epilogue: direct sum-exp (logits bounded; no max needed in fp32)
    float bb[4];
    #pragma unroll
    for (int ni = 0; ni < 4; ++ni)
        bb[ni] = biasp[cb * 256 + wc * 64 + ni * 16 + l15];

    #pragma unroll
    for (int mi = 0; mi < 8; ++mi) {
        #pragma unroll
        for (int j = 0; j < 4; ++j) {
            const int rl = wr * 128 + mi * 16 + lhi * 4 + j;
            const int lab = labels[rb * 256 + rl];
            float sv = 0.f, tv = 0.f;
            #pragma unroll
            for (int ni = 0; ni < 4; ++ni) {
                const float v = acc[mi][ni][j] + bb[ni];
                sv += __expf(v);
                const int gc = cb * 256 + wc * 64 + ni * 16 + l15;
                tv = (gc == lab) ? v : tv;
            }
            #pragma unroll
            for (int d = 1; d < 16; d <<= 1) {
                sv += __shfl_xor(sv, d);
                tv += __shfl_xor(tv, d);
            }
            if (l15 == 0) { red2[rl][wc][0] = sv; red2[rl][wc][1] = tv; }
        }
    }
    __syncthreads();
    if (tid < 256) {
        const float sv = red2[tid][0][0] + red2[tid][1][0] + red2[tid][2][0] + red2[tid][3][0];
        const float tv = red2[tid][0][1] + red2[tid][1][1] + red2[tid][2][1] + red2[tid][3][1];
        const int grow = rb * 256 + tid;
        s_part[(size_t)cb * B_ROWS + grow]  = sv;
        tl_part[(size_t)cb * B_ROWS + grow] = tv;
    }
}

// ---- combine partials across the 8 column blocks, per-row aux loss ----
__global__ __launch_bounds__(256)
void rowcomb_kernel(const float* __restrict__ s_part, const float* __restrict__ tl_part,
                    float* __restrict__ aux_part)
{
    const int row = blockIdx.x * 256 + threadIdx.x;
    float s = 0.f, t = 0.f;
    #pragma unroll
    for (int p = 0; p < NCB; ++p) {
        s += s_part[(size_t)p * B_ROWS + row];
        t += tl_part[(size_t)p * B_ROWS + row];
    }
    float acc = __logf(s) - t;
    for (int d = 32; d >= 1; d >>= 1) acc += __shfl_xor(acc, d);
    __shared__ float red[4];
    const int wid = threadIdx.x >> 6, lane = threadIdx.x & 63;
    if (lane == 0) red[wid] = acc;
    __syncthreads();
    if (threadIdx.x == 0) aux_part[blockIdx.x] = red[0] + red[1] + red[2] + red[3];
}

__global__ __launch_bounds__(256)
void final_kernel(const float* __restrict__ fisher_part, const float* __restrict__ aux_part,
                  float* __restrict__ out)
{
    const int tid = threadIdx.x;
    float acc = fisher_part[tid] + fisher_part[256 + tid];
    if (tid < 64) acc += aux_part[tid];
    for (int d = 32; d >= 1; d >>= 1) acc += __shfl_xor(acc, d);
    __shared__ float red[4];
    const int wid = tid >> 6, lane = tid & 63;
    if (lane == 0) red[wid] = acc;
    __syncthreads();
    if (tid == 0) out[0] = (red[0] + red[1] + red[2] + red[3]) * (1.0f / (float)B_ROWS);
}

extern "C" void kernel_launch(void* const* d_in, const int* in_sizes, int n_in,
                              void* d_out, int out_size, void* d_ws, size_t ws_size,
                              hipStream_t stream)
{
    (void)in_sizes; (void)n_in; (void)out_size; (void)ws_size;
    const float* feat    = (const float*)d_in[0];
    const int*   labels  = (const int*)  d_in[1];
    const float* centers = (const float*)d_in[2];
    const float* W       = (const float*)d_in[3];
    const float* bias    = (const float*)d_in[4];
    float* out = (float*)d_out;
    char* ws = (char*)d_ws;

    const size_t szA    = (size_t)NRB * PANEL_B;   // 33,554,432
    const size_t szB    = (size_t)NCB * PANEL_B;   //  4,194,304
    const size_t szBias = (size_t)C_PAD * 4;

    char* A_pre = ws;
    char* B_pre = ws + szA;
    float* bias_pad    = (float*)(ws + szA + szB);
    float* s_part      = (float*)(ws + szA + szB + szBias);
    float* tl_part     = s_part + (size_t)NCB * B_ROWS;
    float* fisher_part = tl_part + (size_t)NCB * B_ROWS;
    float* aux_part    = fisher_part + 512;

    prepA_kernel<<<512, 256, 0, stream>>>(feat, labels, centers, A_pre, fisher_part);
    prepB_kernel<<<128, 256, 0, stream>>>(W, bias, B_pre, bias_pad);
    gemm_kernel<<<NRB * NCB, 512, 0, stream>>>(labels, bias_pad, A_pre, B_pre, s_part, tl_part);
    rowcomb_kernel<<<B_ROWS / 256, 256, 0, stream>>>(s_part, tl_part, aux_part);
    final_kernel<<<1, 256, 0, stream>>>(fisher_part, aux_part, out);
}

// Round 7
// 132.396 us; speedup vs baseline: 1.0367x; 1.0367x over previous
//
#include <hip/hip_runtime.h>
#include <stdint.h>

#define B_ROWS 16384
#define C_CLS  2000
#define C_PAD  2048
#define F_DIM  1024
#define KT     16                      // K-tiles of 64 (2 khalf regions each)
#define NRB    64                      // gemm row blocks (256 rows)
#define NCB    8                       // gemm col blocks (256 cols)
#define REG_B  16384                   // bytes per (tile,khalf) region: 256 rows x 32 k bf16
#define PANEL_B ((size_t)KT * 2 * REG_B)  // 512 KB per 256-row/col panel

typedef float  f32x4  __attribute__((ext_vector_type(4)));
typedef __bf16 bf16x8 __attribute__((ext_vector_type(8)));
typedef unsigned short u16x8 __attribute__((ext_vector_type(8)));

__device__ __forceinline__ unsigned short f2bf(float f) {
    union { float f; uint32_t u; } v; v.f = f;
    uint32_t u = v.u;
    return (unsigned short)((u + 0x7fffu + ((u >> 16) & 1u)) >> 16);  // RNE
}

__device__ __forceinline__ void gl_lds16(const void* g, void* l) {
    __builtin_amdgcn_global_load_lds(
        (const __attribute__((address_space(1))) unsigned int*)g,
        (__attribute__((address_space(3))) unsigned int*)l, 16, 0, 0);
}

// Region layout (16KB, 256 rows x 32 k bf16): line j(0..127) of 128B holds rows
// j (rh=0) and j+128 (rh=1); 16B chunk m = rh*4 + c stored at j*128 + ((m^(j&7))<<4).
// Read chunk key (x*4+lhi)^(l15&7) == R4's measured-conflict-free pattern.

// ---- prepass A: feat -> bf16 regions, fused fisher. grid 512 = rt(128) x g(4) ----
__global__ __launch_bounds__(256)
void prepA_kernel(const float* __restrict__ feat, const int* __restrict__ labels,
                  const float* __restrict__ centers,
                  char* __restrict__ A_pre, float* __restrict__ fisher_part)
{
    const int rt = blockIdx.x >> 2, g = blockIdx.x & 3;
    const int rb = rt >> 1, rh = rt & 1;
    const int tid = threadIdx.x;
    const int r = tid >> 1, h = tid & 1;      // r = line j, h = khalf
    const int grow = rt * 128 + r;
    const int lab = labels[grow];
    const float* frow = feat    + (size_t)grow * F_DIM;
    const float* crow = centers + (size_t)lab  * F_DIM;
    float facc = 0.f;
    #pragma unroll
    for (int q = 0; q < 4; ++q) {
        const int kt = g * 4 + q;
        char* dst = A_pre + (size_t)rb * PANEL_B + (size_t)(kt * 2 + h) * REG_B + r * 128;
        const int kb = kt * 64 + h * 32;
        #pragma unroll
        for (int cc = 0; cc < 4; ++cc) {
            float4 f0 = *(const float4*)(frow + kb + cc * 8);
            float4 f1 = *(const float4*)(frow + kb + cc * 8 + 4);
            float4 c0 = *(const float4*)(crow + kb + cc * 8);
            float4 c1 = *(const float4*)(crow + kb + cc * 8 + 4);
            float d0 = f0.x - c0.x, d1 = f0.y - c0.y, d2 = f0.z - c0.z, d3 = f0.w - c0.w;
            float d4 = f1.x - c1.x, d5 = f1.y - c1.y, d6 = f1.z - c1.z, d7 = f1.w - c1.w;
            facc += d0*d0 + d1*d1 + d2*d2 + d3*d3 + d4*d4 + d5*d5 + d6*d6 + d7*d7;
            u16x8 o = { f2bf(f0.x), f2bf(f0.y), f2bf(f0.z), f2bf(f0.w),
                        f2bf(f1.x), f2bf(f1.y), f2bf(f1.z), f2bf(f1.w) };
            *(u16x8*)(dst + (((rh * 4 + cc) ^ (r & 7)) << 4)) = o;
        }
    }
    for (int d = 32; d >= 1; d >>= 1) facc += __shfl_xor(facc, d);
    __shared__ float redw[4];
    const int wid = tid >> 6, lane = tid & 63;
    if (lane == 0) redw[wid] = facc;
    __syncthreads();
    if (tid == 0) fisher_part[blockIdx.x] = redw[0] + redw[1] + redw[2] + redw[3];
}

// ---- prepass B: W -> bf16 regions, zero-pad; bias pad folded. grid 128 = ct(16) x ktg(8) ----
__global__ __launch_bounds__(256)
void prepB_kernel(const float* __restrict__ W, const float* __restrict__ bias,
                  char* __restrict__ B_pre, float* __restrict__ bias_pad)
{
    const int ct = blockIdx.x >> 3, ktg = blockIdx.x & 7;
    const int cb = ct >> 1, rh = ct & 1;
    const int tid = threadIdx.x;
    const int rcol = tid >> 1, h = tid & 1;
    const int gc = ct * 128 + rcol;
    const int kt = ktg * 2 + h;
    #pragma unroll
    for (int kh = 0; kh < 2; ++kh) {
        char* dst = B_pre + (size_t)cb * PANEL_B + (size_t)(kt * 2 + kh) * REG_B + rcol * 128;
        if (gc < C_CLS) {
            const float* src = W + (size_t)gc * F_DIM + kt * 64 + kh * 32;
            #pragma unroll
            for (int cc = 0; cc < 4; ++cc) {
                float4 f0 = *(const float4*)(src + cc * 8);
                float4 f1 = *(const float4*)(src + cc * 8 + 4);
                u16x8 o = { f2bf(f0.x), f2bf(f0.y), f2bf(f0.z), f2bf(f0.w),
                            f2bf(f1.x), f2bf(f1.y), f2bf(f1.z), f2bf(f1.w) };
                *(u16x8*)(dst + (((rh * 4 + cc) ^ (rcol & 7)) << 4)) = o;
            }
        } else {
            u16x8 z = {0,0,0,0,0,0,0,0};
            #pragma unroll
            for (int cc = 0; cc < 4; ++cc)
                *(u16x8*)(dst + (((rh * 4 + cc) ^ (rcol & 7)) << 4)) = z;
        }
    }
    if (blockIdx.x < C_PAD / 256) {
        const int i = blockIdx.x * 256 + tid;
        bias_pad[i] = (i < C_CLS) ? bias[i] : -1e30f;
    }
}

// ---- 256x256 MFMA GEMM, 8-phase pipeline, conflict-free LDS, sum-exp epilogue ----
// LDS per buf (64KB): [A k0 16K][A k1 16K][B k0 16K][B k1 16K]; 2 bufs = 128KB
__global__ __launch_bounds__(512, 2)
void gemm_kernel(const int* __restrict__ labels, const float* __restrict__ biasp,
                 const char* __restrict__ A_pre, const char* __restrict__ B_pre,
                 float* __restrict__ s_part, float* __restrict__ tl_part)
{
    __shared__ alignas(128) char smem[131072];
    __shared__ float red2[256][4][2];

    const int cpx = gridDim.x >> 3;                 // XCD swizzle: same-XCD blocks share rb
    const int wg = (blockIdx.x & 7) * cpx + (blockIdx.x >> 3);
    const int cb = wg & 7;
    const int rb = wg >> 3;

    const int tid = threadIdx.x;
    const int w = tid >> 6, lane = tid & 63;
    const int l15 = lane & 15, lhi = lane >> 4;
    const int wr = w >> 2, wc = w & 3;

    const char* Asrc = A_pre + (size_t)rb * PANEL_B;
    const char* Bsrc = B_pre + (size_t)cb * PANEL_B;

    // conflict-free swizzled ds_read byte offsets within a (A|B,khalf) region
    int aoff[8], boff[4];
    #pragma unroll
    for (int mi = 0; mi < 8; ++mi) {
        const int j = mi * 16 + l15;                // line = row&127; rh = wr
        aoff[mi] = j * 128 + (((wr * 4 + lhi) ^ (j & 7)) << 4);
    }
    #pragma unroll
    for (int ni = 0; ni < 4; ++ni) {
        const int j = (wc & 1) * 64 + ni * 16 + l15;  // line = col&127; rh = wc>>1
        boff[ni] = j * 128 + ((((wc >> 1) * 4 + lhi) ^ (j & 7)) << 4);
    }

    f32x4 acc[8][4];
    #pragma unroll
    for (int mi = 0; mi < 8; ++mi)
        #pragma unroll
        for (int ni = 0; ni < 4; ++ni) acc[mi][ni] = (f32x4){0.f, 0.f, 0.f, 0.f};

    auto STAGE = [&](const char* srcreg, int ldsreg) {  // 16KB region, 2 loads/thread
        const char* s = srcreg + w * 2048 + lane * 16;
        char* d = smem + ldsreg + w * 2048;             // wave-uniform dst base
        gl_lds16(s, d);
        gl_lds16(s + 1024, d + 1024);
    };

    bf16x8 bv[4];

#define PHASE(BUFOFF, KF, MLO, LOADB, DOSTAGE, SREG, LREG, WAITN) do {                \
    const char* Ab_ = smem + (BUFOFF) + (KF) * 16384;                                 \
    const char* Bb_ = smem + (BUFOFF) + 32768 + (KF) * 16384;                         \
    bf16x8 af_[4];                                                                    \
    if (LOADB) {                                                                      \
        _Pragma("unroll")                                                             \
        for (int ni_ = 0; ni_ < 4; ++ni_)                                             \
            bv[ni_] = *(const bf16x8*)(Bb_ + boff[ni_]);                              \
    }                                                                                 \
    _Pragma("unroll")                                                                 \
    for (int mi_ = 0; mi_ < 4; ++mi_)                                                 \
        af_[mi_] = *(const bf16x8*)(Ab_ + aoff[(MLO) + mi_]);                         \
    __builtin_amdgcn_sched_barrier(0);                                                \
    if (DOSTAGE) STAGE(SREG, LREG);                                                   \
    asm volatile("s_waitcnt vmcnt(" #WAITN ")" ::: "memory");                         \
    __builtin_amdgcn_sched_barrier(0);                                                \
    __builtin_amdgcn_s_barrier();                                                     \
    __builtin_amdgcn_sched_barrier(0);                                                \
    __builtin_amdgcn_s_setprio(1);                                                    \
    _Pragma("unroll")                                                                 \
    for (int mi_ = 0; mi_ < 4; ++mi_)                                                 \
        _Pragma("unroll")                                                             \
        for (int ni_ = 0; ni_ < 4; ++ni_)                                             \
            acc[(MLO) + mi_][ni_] = __builtin_amdgcn_mfma_f32_16x16x32_bf16(          \
                af_[mi_], bv[ni_], acc[(MLO) + mi_][ni_], 0, 0, 0);                   \
    __builtin_amdgcn_s_setprio(0);                                                    \
    __builtin_amdgcn_sched_barrier(0);                                                \
    __builtin_amdgcn_s_barrier();                                                     \
} while (0)

    // prologue: tile0 all regions + tile1 khalf0
    STAGE(Asrc,             0);       // A(0,k0)
    STAGE(Bsrc,             32768);   // B(0,k0)
    STAGE(Asrc + REG_B,     16384);   // A(0,k1)
    STAGE(Bsrc + REG_B,     49152);   // B(0,k1)
    STAGE(Asrc + 2 * REG_B, 65536);   // A(1,k0)
    STAGE(Bsrc + 2 * REG_B, 98304);   // B(1,k0)
    asm volatile("s_waitcnt vmcnt(4)" ::: "memory");
    __builtin_amdgcn_sched_barrier(0);
    __builtin_amdgcn_s_barrier();

    #pragma unroll 1
    for (int i = 0; i < 7; ++i) {
        const char* At = Asrc + (size_t)(4 * i) * REG_B;
        const char* Bt = Bsrc + (size_t)(4 * i) * REG_B;
        // buf0 = tile 2i, buf1 = tile 2i+1; stage map per region-lifetime analysis
        PHASE(0,     0, 0, 1, 1, At + 3 * REG_B,  81920, 8);   // A(2i+1,k1) -> buf1.Ak1
        PHASE(0,     0, 4, 0, 1, Bt + 3 * REG_B, 114688, 8);   // B(2i+1,k1) -> buf1.Bk1
        PHASE(0,     1, 0, 1, 1, At + 4 * REG_B,      0, 8);   // A(2i+2,k0) -> buf0.Ak0
        PHASE(0,     1, 4, 0, 1, Bt + 4 * REG_B,  32768, 8);   // B(2i+2,k0) -> buf0.Bk0
        PHASE(65536, 0, 0, 1, 1, At + 5 * REG_B,  16384, 8);   // A(2i+2,k1) -> buf0.Ak1
        PHASE(65536, 0, 4, 0, 1, Bt + 5 * REG_B,  49152, 8);   // B(2i+2,k1) -> buf0.Bk1
        PHASE(65536, 1, 0, 1, 1, At + 6 * REG_B,  65536, 8);   // A(2i+3,k0) -> buf1.Ak0
        PHASE(65536, 1, 4, 0, 1, Bt + 6 * REG_B,  98304, 8);   // B(2i+3,k0) -> buf1.Bk0
    }
    // tail i = 7: tiles 14 (buf0), 15 (buf1); only tile-15 k1 still needs staging
    PHASE(0,     0, 0, 1, 1, Asrc + 31 * REG_B,  81920, 8);
    PHASE(0,     0, 4, 0, 1, Bsrc + 31 * REG_B, 114688, 8);
    PHASE(0,     1, 0, 1, 0, Asrc, 0, 8);
    PHASE(0,     1, 4, 0, 0, Asrc, 0, 8);
    PHASE(65536, 0, 0, 1, 0, Asrc, 0, 8);
    PHASE(65536, 0, 4, 0, 0, Asrc, 0, 8);
    PHASE(65536, 1, 0, 1, 0, Asrc, 0, 0);   // drain: tail-staged Ak1/Bk1 must be resident
    PHASE(65536, 1, 4, 0, 0, Asrc, 0, 0);
#undef PHASE

    // epilogue: direct sum-exp (logits bounded; no max needed in fp32)
    float bb[4];
    #pragma unroll
    for (int ni = 0; ni < 4; ++ni)
        bb[ni] = biasp[cb * 256 + wc * 64 + ni * 16 + l15];

    #pragma unroll
    for (int mi = 0; mi < 8; ++mi) {
        #pragma unroll
        for (int j = 0; j < 4; ++j) {
            const int rl = wr * 128 + mi * 16 + lhi * 4 + j;
            const int lab = labels[rb * 256 + rl];
            float sv = 0.f, tv = 0.f;
            #pragma unroll
            for (int ni = 0; ni < 4; ++ni) {
                const float v = acc[mi][ni][j] + bb[ni];
                sv += __expf(v);
                const int gc = cb * 256 + wc * 64 + ni * 16 + l15;
                tv = (gc == lab) ? v : tv;
            }
            #pragma unroll
            for (int d = 1; d < 16; d <<= 1) {
                sv += __shfl_xor(sv, d);
                tv += __shfl_xor(tv, d);
            }
            if (l15 == 0) { red2[rl][wc][0] = sv; red2[rl][wc][1] = tv; }
        }
    }
    __syncthreads();
    if (tid < 256) {
        const float sv = red2[tid][0][0] + red2[tid][1][0] + red2[tid][2][0] + red2[tid][3][0];
        const float tv = red2[tid][0][1] + red2[tid][1][1] + red2[tid][2][1] + red2[tid][3][1];
        const int grow = rb * 256 + tid;
        s_part[(size_t)cb * B_ROWS + grow]  = sv;
        tl_part[(size_t)cb * B_ROWS + grow] = tv;
    }
}

// ---- combine partials across the 8 column blocks, per-row aux loss ----
__global__ __launch_bounds__(256)
void rowcomb_kernel(const float* __restrict__ s_part, const float* __restrict__ tl_part,
                    float* __restrict__ aux_part)
{
    const int row = blockIdx.x * 256 + threadIdx.x;
    float s = 0.f, t = 0.f;
    #pragma unroll
    for (int p = 0; p < NCB; ++p) {
        s += s_part[(size_t)p * B_ROWS + row];
        t += tl_part[(size_t)p * B_ROWS + row];
    }
    float acc = __logf(s) - t;
    for (int d = 32; d >= 1; d >>= 1) acc += __shfl_xor(acc, d);
    __shared__ float red[4];
    const int wid = threadIdx.x >> 6, lane = threadIdx.x & 63;
    if (lane == 0) red[wid] = acc;
    __syncthreads();
    if (threadIdx.x == 0) aux_part[blockIdx.x] = red[0] + red[1] + red[2] + red[3];
}

__global__ __launch_bounds__(256)
void final_kernel(const float* __restrict__ fisher_part, const float* __restrict__ aux_part,
                  float* __restrict__ out)
{
    const int tid = threadIdx.x;
    float acc = fisher_part[tid] + fisher_part[256 + tid];
    if (tid < 64) acc += aux_part[tid];
    for (int d = 32; d >= 1; d >>= 1) acc += __shfl_xor(acc, d);
    __shared__ float red[4];
    const int wid = tid >> 6, lane = tid & 63;
    if (lane == 0) red[wid] = acc;
    __syncthreads();
    if (tid == 0) out[0] = (red[0] + red[1] + red[2] + red[3]) * (1.0f / (float)B_ROWS);
}

extern "C" void kernel_launch(void* const* d_in, const int* in_sizes, int n_in,
                              void* d_out, int out_size, void* d_ws, size_t ws_size,
                              hipStream_t stream)
{
    (void)in_sizes; (void)n_in; (void)out_size; (void)ws_size;
    const float* feat    = (const float*)d_in[0];
    const int*   labels  = (const int*)  d_in[1];
    const float* centers = (const float*)d_in[2];
    const float* W       = (const float*)d_in[3];
    const float* bias    = (const float*)d_in[4];
    float* out = (float*)d_out;
    char* ws = (char*)d_ws;

    const size_t szA    = (size_t)NRB * PANEL_B;   // 33,554,432
    const size_t szB    = (size_t)NCB * PANEL_B;   //  4,194,304
    const size_t szBias = (size_t)C_PAD * 4;

    char* A_pre = ws;
    char* B_pre = ws + szA;
    float* bias_pad    = (float*)(ws + szA + szB);
    float* s_part      = (float*)(ws + szA + szB + szBias);
    float* tl_part     = s_part + (size_t)NCB * B_ROWS;
    float* fisher_part = tl_part + (size_t)NCB * B_ROWS;
    float* aux_part    = fisher_part + 512;

    prepA_kernel<<<512, 256, 0, stream>>>(feat, labels, centers, A_pre, fisher_part);
    prepB_kernel<<<128, 256, 0, stream>>>(W, bias, B_pre, bias_pad);
    gemm_kernel<<<NRB * NCB, 512, 0, stream>>>(labels, bias_pad, A_pre, B_pre, s_part, tl_part);
    rowcomb_kernel<<<B_ROWS / 256, 256, 0, stream>>>(s_part, tl_part, aux_part);
    final_kernel<<<1, 256, 0, stream>>>(fisher_part, aux_part, out);
}

// Round 8
// 101.894 us; speedup vs baseline: 1.3470x; 1.2993x over previous
//
#include <hip/hip_runtime.h>
#include <stdint.h>

#define B_ROWS 16384
#define C_CLS  2000
#define C_PAD  2048
#define F_DIM  1024
#define KT     16                         // K-tiles of 64
#define NRB    64                         // gemm row blocks (256 rows)
#define NCB    8                          // gemm col blocks (256 cols)
#define TILE8  16384                      // bytes per 256x64 fp8 tile image (A or B)
#define PANEL_B ((size_t)KT * TILE8)      // 256 KB per 256-row/col panel

typedef float f32x4 __attribute__((ext_vector_type(4)));
typedef long long i64x2 __attribute__((ext_vector_type(2)));

#define SCALE_F 4.0f
#define SCALE_W 16.0f
#define INV_SCALE 0.015625f               // 1/64

__device__ __forceinline__ void gl_lds16(const void* g, void* l) {
    __builtin_amdgcn_global_load_lds(
        (const __attribute__((address_space(1))) unsigned int*)g,
        (__attribute__((address_space(3))) unsigned int*)l, 16, 0, 0);
}

__device__ __forceinline__ unsigned int pk4(float a, float b, float c, float d) {
    int u = __builtin_amdgcn_cvt_pk_fp8_f32(a, b, 0, false);   // bytes 0,1
    u = __builtin_amdgcn_cvt_pk_fp8_f32(c, d, u, true);        // bytes 2,3
    return (unsigned int)u;
}

// Tile image (16KB = 256 rows x 64 k fp8): line j(0..127) of 128B; 16B slot
// t = rh*4 + lhi (rh = row>=128) at byte ((t ^ (j&7))<<4); slot = [kf0: k=lhi*8..+8][kf1: k=32+lhi*8..+8].
// GEMM read key (wr*4+lhi)^(l15&7) == R7's measured-conflict-free pattern.

// ---- prepass A: feat -> fp8 images (x4), fused fisher. grid 512 = rt(128) x g(4) ----
__global__ __launch_bounds__(256)
void prepA_kernel(const float* __restrict__ feat, const int* __restrict__ labels,
                  const float* __restrict__ centers,
                  char* __restrict__ A_pre, float* __restrict__ fisher_part)
{
    const int rt = blockIdx.x >> 2, g = blockIdx.x & 3;
    const int rb = rt >> 1, rh = rt & 1;
    const int tid = threadIdx.x;
    const int r = tid >> 1, h = tid & 1;
    const int grow = rt * 128 + r;
    const int lab = labels[grow];
    const float* frow = feat    + (size_t)grow * F_DIM;
    const float* crow = centers + (size_t)lab  * F_DIM;
    char* dbase = A_pre + (size_t)rb * PANEL_B + r * 128;
    float facc = 0.f;
    #pragma unroll
    for (int q = 0; q < 4; ++q) {
        const int kt = g * 4 + q;
        char* dst = dbase + kt * TILE8;
        #pragma unroll
        for (int u = 0; u < 2; ++u) {
            const int lhi = h * 2 + u;
            const int k0 = kt * 64 + lhi * 8;
            float4 a0 = *(const float4*)(frow + k0);
            float4 a1 = *(const float4*)(frow + k0 + 4);
            float4 a2 = *(const float4*)(frow + k0 + 32);
            float4 a3 = *(const float4*)(frow + k0 + 36);
            float4 c0 = *(const float4*)(crow + k0);
            float4 c1 = *(const float4*)(crow + k0 + 4);
            float4 c2 = *(const float4*)(crow + k0 + 32);
            float4 c3 = *(const float4*)(crow + k0 + 36);
            float d0 = a0.x-c0.x, d1 = a0.y-c0.y, d2 = a0.z-c0.z, d3 = a0.w-c0.w;
            float d4 = a1.x-c1.x, d5 = a1.y-c1.y, d6 = a1.z-c1.z, d7 = a1.w-c1.w;
            facc += d0*d0 + d1*d1 + d2*d2 + d3*d3 + d4*d4 + d5*d5 + d6*d6 + d7*d7;
            d0 = a2.x-c2.x; d1 = a2.y-c2.y; d2 = a2.z-c2.z; d3 = a2.w-c2.w;
            d4 = a3.x-c3.x; d5 = a3.y-c3.y; d6 = a3.z-c3.z; d7 = a3.w-c3.w;
            facc += d0*d0 + d1*d1 + d2*d2 + d3*d3 + d4*d4 + d5*d5 + d6*d6 + d7*d7;
            uint4 o = { pk4(SCALE_F*a0.x, SCALE_F*a0.y, SCALE_F*a0.z, SCALE_F*a0.w),
                        pk4(SCALE_F*a1.x, SCALE_F*a1.y, SCALE_F*a1.z, SCALE_F*a1.w),
                        pk4(SCALE_F*a2.x, SCALE_F*a2.y, SCALE_F*a2.z, SCALE_F*a2.w),
                        pk4(SCALE_F*a3.x, SCALE_F*a3.y, SCALE_F*a3.z, SCALE_F*a3.w) };
            const int t = rh * 4 + lhi;
            *(uint4*)(dst + ((t ^ (r & 7)) << 4)) = o;
        }
    }
    for (int d = 32; d >= 1; d >>= 1) facc += __shfl_xor(facc, d);
    __shared__ float redw[4];
    const int wid = tid >> 6, lane = tid & 63;
    if (lane == 0) redw[wid] = facc;
    __syncthreads();
    if (tid == 0) fisher_part[blockIdx.x] = redw[0] + redw[1] + redw[2] + redw[3];
}

// ---- prepass B: W -> fp8 images (x16), zero-pad; bias pad folded. grid 128 = ct(16) x ktg(8) ----
__global__ __launch_bounds__(256)
void prepB_kernel(const float* __restrict__ W, const float* __restrict__ bias,
                  char* __restrict__ B_pre, float* __restrict__ bias_pad)
{
    const int ct = blockIdx.x >> 3, ktg = blockIdx.x & 7;
    const int cb = ct >> 1, rh = ct & 1;
    const int tid = threadIdx.x;
    const int rcol = tid >> 1, h = tid & 1;
    const int gc = ct * 128 + rcol;
    char* dbase = B_pre + (size_t)cb * PANEL_B + rcol * 128;
    #pragma unroll
    for (int q = 0; q < 2; ++q) {
        const int kt = ktg * 2 + q;
        char* dst = dbase + kt * TILE8;
        #pragma unroll
        for (int u = 0; u < 2; ++u) {
            const int lhi = h * 2 + u;
            const int t = rh * 4 + lhi;
            uint4 o;
            if (gc < C_CLS) {
                const float* src = W + (size_t)gc * F_DIM + kt * 64 + lhi * 8;
                float4 a0 = *(const float4*)(src);
                float4 a1 = *(const float4*)(src + 4);
                float4 a2 = *(const float4*)(src + 32);
                float4 a3 = *(const float4*)(src + 36);
                o = (uint4){ pk4(SCALE_W*a0.x, SCALE_W*a0.y, SCALE_W*a0.z, SCALE_W*a0.w),
                             pk4(SCALE_W*a1.x, SCALE_W*a1.y, SCALE_W*a1.z, SCALE_W*a1.w),
                             pk4(SCALE_W*a2.x, SCALE_W*a2.y, SCALE_W*a2.z, SCALE_W*a2.w),
                             pk4(SCALE_W*a3.x, SCALE_W*a3.y, SCALE_W*a3.z, SCALE_W*a3.w) };
            } else {
                o = (uint4){0u, 0u, 0u, 0u};
            }
            *(uint4*)(dst + ((t ^ (rcol & 7)) << 4)) = o;
        }
    }
    if (blockIdx.x < C_PAD / 256) {
        const int i = blockIdx.x * 256 + tid;
        bias_pad[i] = (i < C_CLS) ? bias[i] : -1e30f;
    }
}

// ---- 256x256 fp8 MFMA GEMM, 3-buffer 4-phase counted-vmcnt pipeline ----
// LDS: 3 bufs x (A 16KB + B 16KB) = 96 KB (+ red2 8 KB)
__global__ __launch_bounds__(512, 2)
void gemm_kernel(const int* __restrict__ labels, const float* __restrict__ biasp,
                 const char* __restrict__ A_pre, const char* __restrict__ B_pre,
                 float* __restrict__ s_part, float* __restrict__ tl_part)
{
    __shared__ alignas(128) char smem[98304];
    __shared__ float red2[256][4][2];

    const int cpx = gridDim.x >> 3;                 // XCD swizzle: same-XCD blocks share rb
    const int wg = (blockIdx.x & 7) * cpx + (blockIdx.x >> 3);
    const int cb = wg & 7;
    const int rb = wg >> 3;

    const int tid = threadIdx.x;
    const int w = tid >> 6, lane = tid & 63;
    const int l15 = lane & 15, lhi = lane >> 4;
    const int wr = w >> 2, wc = w & 3;

    const char* Asrc = A_pre + (size_t)rb * PANEL_B;
    const char* Bsrc = B_pre + (size_t)cb * PANEL_B;

    // conflict-free swizzled ds_read_b128 offsets (each read = both kf fragments)
    int aoff[8], boff[4];
    #pragma unroll
    for (int mi = 0; mi < 8; ++mi) {
        const int j = mi * 16 + l15;
        aoff[mi] = j * 128 + (((wr * 4 + lhi) ^ (l15 & 7)) << 4);
    }
    #pragma unroll
    for (int ni = 0; ni < 4; ++ni) {
        const int j = (wc & 1) * 64 + ni * 16 + l15;
        boff[ni] = 16384 + j * 128 + ((((wc >> 1) * 4 + lhi) ^ (l15 & 7)) << 4);
    }

    f32x4 acc[8][4];
    #pragma unroll
    for (int mi = 0; mi < 8; ++mi)
        #pragma unroll
        for (int ni = 0; ni < 4; ++ni) acc[mi][ni] = (f32x4){0.f, 0.f, 0.f, 0.f};

    const int woff = w * 1024;

#define MFMA16(MLO, KF) do {                                                          \
    __builtin_amdgcn_s_setprio(1);                                                    \
    _Pragma("unroll")                                                                 \
    for (int mi_ = 0; mi_ < 4; ++mi_)                                                 \
        _Pragma("unroll")                                                             \
        for (int ni_ = 0; ni_ < 4; ++ni_)                                             \
            acc[(MLO) + mi_][ni_] = __builtin_amdgcn_mfma_f32_16x16x32_fp8_fp8(       \
                av2[(MLO) + mi_][KF], bv2[ni_][KF], acc[(MLO) + mi_][ni_], 0, 0, 0);  \
    __builtin_amdgcn_s_setprio(0);                                                    \
} while (0)

#define STAGEQ(SRCQ, LOFF) do {                                                       \
    gl_lds16((SRCQ) + tid * 16, smem + (LOFF) + woff);                                \
} while (0)

#define FENCE __builtin_amdgcn_sched_barrier(0)
#define WAITV(N) do { asm volatile("s_waitcnt vmcnt(" #N ")" ::: "memory"); } while (0)
#define BAR __builtin_amdgcn_s_barrier()

    // prologue: tiles 0,1 -> bufs 0,1 (4 quarters each)
    STAGEQ(Asrc,                 0);
    STAGEQ(Asrc + 8192,          8192);
    STAGEQ(Bsrc,                 16384);
    STAGEQ(Bsrc + 8192,          24576);
    STAGEQ(Asrc + TILE8,         32768);
    STAGEQ(Asrc + TILE8 + 8192,  40960);
    STAGEQ(Bsrc + TILE8,         49152);
    STAGEQ(Bsrc + TILE8 + 8192,  57344);
    WAITV(4);
    FENCE;
    BAR;

    int bo = 0, so = 65536;
    #pragma unroll 1
    for (int kt = 0; kt < KT; ++kt) {
        const char* base = smem + bo;
        const bool st = (kt < KT - 2);
        const char* sA = Asrc + (size_t)(kt + 2) * TILE8;
        const char* sB = Bsrc + (size_t)(kt + 2) * TILE8;
        i64x2 av2[8], bv2[4];
        // P0: all B + A lo-half reads; stage A.lo; MFMA kf0 mi0-3
        #pragma unroll
        for (int ni = 0; ni < 4; ++ni) bv2[ni] = *(const i64x2*)(base + boff[ni]);
        #pragma unroll
        for (int mi = 0; mi < 4; ++mi) av2[mi] = *(const i64x2*)(base + aoff[mi]);
        FENCE;
        if (st) STAGEQ(sA, so);
        if (kt == KT - 1) { WAITV(0); } else { WAITV(4); }
        FENCE;
        MFMA16(0, 0);
        FENCE; BAR;
        // P1: A hi-half reads; stage A.hi; MFMA kf0 mi4-7
        #pragma unroll
        for (int mi = 4; mi < 8; ++mi) av2[mi] = *(const i64x2*)(base + aoff[mi]);
        FENCE;
        if (st) STAGEQ(sA + 8192, so + 8192);
        WAITV(4);
        FENCE;
        MFMA16(4, 0);
        FENCE; BAR;
        // P2: no reads; stage B.lo; MFMA kf1 mi0-3
        if (st) STAGEQ(sB, so + 16384);
        WAITV(4);
        FENCE;
        MFMA16(0, 1);
        FENCE; BAR;
        // P3: no reads; stage B.hi; MFMA kf1 mi4-7
        if (st) STAGEQ(sB + 8192, so + 24576);
        WAITV(4);
        FENCE;
        MFMA16(4, 1);
        FENCE; BAR;
        bo = (bo == 65536) ? 0 : bo + 32768;
        so = (so == 65536) ? 0 : so + 32768;
    }
#undef MFMA16
#undef STAGEQ
#undef FENCE
#undef WAITV
#undef BAR

    // epilogue: rescale + direct sum-exp (logits ~N(0,1); no max needed in fp32)
    float bb[4];
    #pragma unroll
    for (int ni = 0; ni < 4; ++ni)
        bb[ni] = biasp[cb * 256 + wc * 64 + ni * 16 + l15];

    #pragma unroll
    for (int mi = 0; mi < 8; ++mi) {
        #pragma unroll
        for (int j = 0; j < 4; ++j) {
            const int rl = wr * 128 + mi * 16 + lhi * 4 + j;
            const int lab = labels[rb * 256 + rl];
            float sv = 0.f, tv = 0.f;
            #pragma unroll
            for (int ni = 0; ni < 4; ++ni) {
                const float v = fmaf(acc[mi][ni][j], INV_SCALE, bb[ni]);
                sv += __expf(v);
                const int gc = cb * 256 + wc * 64 + ni * 16 + l15;
                tv = (gc == lab) ? v : tv;
            }
            #pragma unroll
            for (int d = 1; d < 16; d <<= 1) {
                sv += __shfl_xor(sv, d);
                tv += __shfl_xor(tv, d);
            }
            if (l15 == 0) { red2[rl][wc][0] = sv; red2[rl][wc][1] = tv; }
        }
    }
    __syncthreads();
    if (tid < 256) {
        const float sv = red2[tid][0][0] + red2[tid][1][0] + red2[tid][2][0] + red2[tid][3][0];
        const float tv = red2[tid][0][1] + red2[tid][1][1] + red2[tid][2][1] + red2[tid][3][1];
        const int grow = rb * 256 + tid;
        s_part[(size_t)cb * B_ROWS + grow]  = sv;
        tl_part[(size_t)cb * B_ROWS + grow] = tv;
    }
}

// ---- combine partials across the 8 column blocks, per-row aux loss ----
__global__ __launch_bounds__(256)
void rowcomb_kernel(const float* __restrict__ s_part, const float* __restrict__ tl_part,
                    float* __restrict__ aux_part)
{
    const int row = blockIdx.x * 256 + threadIdx.x;
    float s = 0.f, t = 0.f;
    #pragma unroll
    for (int p = 0; p < NCB; ++p) {
        s += s_part[(size_t)p * B_ROWS + row];
        t += tl_part[(size_t)p * B_ROWS + row];
    }
    float acc = __logf(s) - t;
    for (int d = 32; d >= 1; d >>= 1) acc += __shfl_xor(acc, d);
    __shared__ float red[4];
    const int wid = threadIdx.x >> 6, lane = threadIdx.x & 63;
    if (lane == 0) red[wid] = acc;
    __syncthreads();
    if (threadIdx.x == 0) aux_part[blockIdx.x] = red[0] + red[1] + red[2] + red[3];
}

__global__ __launch_bounds__(256)
void final_kernel(const float* __restrict__ fisher_part, const float* __restrict__ aux_part,
                  float* __restrict__ out)
{
    const int tid = threadIdx.x;
    float acc = fisher_part[tid] + fisher_part[256 + tid];
    if (tid < 64) acc += aux_part[tid];
    for (int d = 32; d >= 1; d >>= 1) acc += __shfl_xor(acc, d);
    __shared__ float red[4];
    const int wid = tid >> 6, lane = tid & 63;
    if (lane == 0) red[wid] = acc;
    __syncthreads();
    if (tid == 0) out[0] = (red[0] + red[1] + red[2] + red[3]) * (1.0f / (float)B_ROWS);
}

extern "C" void kernel_launch(void* const* d_in, const int* in_sizes, int n_in,
                              void* d_out, int out_size, void* d_ws, size_t ws_size,
                              hipStream_t stream)
{
    (void)in_sizes; (void)n_in; (void)out_size; (void)ws_size;
    const float* feat    = (const float*)d_in[0];
    const int*   labels  = (const int*)  d_in[1];
    const float* centers = (const float*)d_in[2];
    const float* W       = (const float*)d_in[3];
    const float* bias    = (const float*)d_in[4];
    float* out = (float*)d_out;
    char* ws = (char*)d_ws;

    const size_t szA    = (size_t)NRB * PANEL_B;   // 16,777,216
    const size_t szB    = (size_t)NCB * PANEL_B;   //  2,097,152
    const size_t szBias = (size_t)C_PAD * 4;

    char* A_pre = ws;
    char* B_pre = ws + szA;
    float* bias_pad    = (float*)(ws + szA + szB);
    float* s_part      = (float*)(ws + szA + szB + szBias);
    float* tl_part     = s_part + (size_t)NCB * B_ROWS;
    float* fisher_part = tl_part + (size_t)NCB * B_ROWS;
    float* aux_part    = fisher_part + 512;

    prepA_kernel<<<512, 256, 0, stream>>>(feat, labels, centers, A_pre, fisher_part);
    prepB_kernel<<<128, 256, 0, stream>>>(W, bias, B_pre, bias_pad);
    gemm_kernel<<<NRB * NCB, 512, 0, stream>>>(labels, bias_pad, A_pre, B_pre, s_part, tl_part);
    rowcomb_kernel<<<B_ROWS / 256, 256, 0, stream>>>(s_part, tl_part, aux_part);
    final_kernel<<<1, 256, 0, stream>>>(fisher_part, aux_part, out);
}